// Round 12
// baseline (713.169 us; speedup 1.0000x reference)
//
#include <hip/hip_runtime.h>
#include <hip/hip_fp16.h>
#include <math.h>

#define EPS 1e-5f
#define N_GRAPHS 128

__device__ __forceinline__ float sigmoidf_(float x) {
    return __fdividef(1.0f, 1.0f + __expf(-x));
}

// ---------------------------------------------------------------------------
// Fused prep: block-range partition.
//  [0,256):  deg histogram      [256,320): fuse_w layer0 (K=128)
//  [320,384): fuse_w layer1 (K=64)        [384,400): per-graph counts
// Fused col c: [0,64)=Wk, [64,128)=Ws, [128,256)= interleaved (q,v).
// ---------------------------------------------------------------------------
__device__ __forceinline__ void fuse_w_body(
    int b0, int blk, int tid,
    const float* __restrict__ Wk, const float* __restrict__ bk,
    const float* __restrict__ Wq, const float* __restrict__ bq,
    const float* __restrict__ Wv, const float* __restrict__ bv,
    const float* __restrict__ Ws, const float* __restrict__ cbv,
    float* __restrict__ Wf, float* __restrict__ bf, int K)
{
    int t = (blk - b0) * 256 + tid;
    int total = K * 256;
    for (int i = t; i < total; i += 64 * 256) {
        int k = i >> 8, c = i & 255;
        const float* W;
        int cc;
        if (c < 64)       { W = Wk; cc = c; }
        else if (c < 128) { W = Ws; cc = c - 64; }
        else { int j = c - 128; cc = j >> 1; W = (j & 1) ? Wv : Wq; }
        Wf[i] = W[k * 64 + cc];
    }
    if (t < 256) {
        int c = t;
        const float* b;
        int cc;
        if (c < 64)       { b = bk;  cc = c; }
        else if (c < 128) { b = cbv; cc = c - 64; }
        else { int j = c - 128; cc = j >> 1; b = (j & 1) ? bv : bq; }
        bf[t] = b[cc];
    }
}

__global__ __launch_bounds__(256) void prep_kernel(
    const int* __restrict__ ei, int* __restrict__ deg, int E,
    const int* __restrict__ batch, float* __restrict__ counts, int N,
    const float* __restrict__ Wk0, const float* __restrict__ bk0,
    const float* __restrict__ Wq0, const float* __restrict__ bq0,
    const float* __restrict__ Wv0, const float* __restrict__ bv0,
    const float* __restrict__ Ws0, const float* __restrict__ cb0,
    float* __restrict__ Wf0, float* __restrict__ bf0,
    const float* __restrict__ Wk1, const float* __restrict__ bk1,
    const float* __restrict__ Wq1, const float* __restrict__ bq1,
    const float* __restrict__ Wv1, const float* __restrict__ bv1,
    const float* __restrict__ Ws1, const float* __restrict__ cb1,
    float* __restrict__ Wf1, float* __restrict__ bf1)
{
    const int blk = blockIdx.x;
    const int tid = threadIdx.x;
    if (blk < 256) {
        int t = blk * 256 + tid;
        for (int e = t; e < E; e += 256 * 256) atomicAdd(&deg[ei[E + e]], 1);
    } else if (blk < 320) {
        fuse_w_body(256, blk, tid, Wk0, bk0, Wq0, bq0, Wv0, bv0, Ws0, cb0,
                    Wf0, bf0, 128);
    } else if (blk < 384) {
        fuse_w_body(320, blk, tid, Wk1, bk1, Wq1, bq1, Wv1, bv1, Ws1, cb1,
                    Wf1, bf1, 64);
    } else {
        const int t = (blk - 384) * 256 + tid;
        const int T = 16 * 256;
        const int chunk = (N + T - 1) / T;
        const int a = t * chunk;
        const int b = min(N, a + chunk);
        int cur = -1;
        float c = 0.0f;
        for (int n = a; n < b; ++n) {
            int gi = batch[n];
            if (gi != cur) {
                if (cur >= 0) atomicAdd(&counts[cur], c);
                cur = gi;
                c = 0.0f;
            }
            c += 1.0f;
        }
        if (cur >= 0) atomicAdd(&counts[cur], c);
    }
}

// ---------------------------------------------------------------------------
// Projection v6: LDS-tiled fp32 GEMM, fused N=256 per block, M=64 tile,
// 8x8 register tile with SPLIT column mapping: thread owns cols
// {4cg..4cg+3} (-> fp32 Y2) and {128+4cg..128+4cg+3} (-> fp16 QV).
// B-reads use the 4cg-stride float4 pattern (measured conflict-free in
// r5-r9); stores are fully contiguous (512B Y2 row / 256B QV row per wave).
// AFF: BN affine computed from stats/g/be, applied while staging X.
// ---------------------------------------------------------------------------
template <int K, bool AFF>
__global__ __launch_bounds__(256) void proj_kernel(
    const float* __restrict__ X, const float* __restrict__ Wf,
    const float* __restrict__ bf,
    const float* __restrict__ stats, const float* __restrict__ g,
    const float* __restrict__ be, float invN,
    float* __restrict__ Y2, unsigned* __restrict__ QV, int N)
{
    __shared__ __attribute__((aligned(16))) float As[16][72];
    __shared__ __attribute__((aligned(16))) float Bs[16][256];
    const int tid = threadIdx.x;
    const int n0 = blockIdx.x * 64;
    const int cg = tid & 31;       // col group: lo=4cg, hi=128+4cg
    const int mg = tid >> 5;       // 8-row group (0..7)
    const int ar = tid >> 2, akq = (tid & 3) * 4;
    const int bk_ = tid >> 4, bcol = (tid & 15) * 16;

    float acc[8][8];
#pragma unroll
    for (int r = 0; r < 8; ++r)
#pragma unroll
        for (int c = 0; c < 8; ++c) acc[r][c] = 0.0f;

    for (int k0 = 0; k0 < K; k0 += 16) {
        float4 av4 = make_float4(0.f, 0.f, 0.f, 0.f);
        int row = n0 + ar;
        if (row < N) av4 = *(const float4*)&X[(size_t)row * K + k0 + akq];
        if constexpr (AFF) {
            float a4[4], b4[4];
#pragma unroll
            for (int i = 0; i < 4; ++i) {
                int c = k0 + akq + i;
                float m = stats[c] * invN;
                float vv = stats[64 + c] * invN - m * m;
                float rs = rsqrtf(vv + EPS) * g[c];
                a4[i] = rs;
                b4[i] = be[c] - m * rs;
            }
            av4.x = fmaf(av4.x, a4[0], b4[0]);
            av4.y = fmaf(av4.y, a4[1], b4[1]);
            av4.z = fmaf(av4.z, a4[2], b4[2]);
            av4.w = fmaf(av4.w, a4[3], b4[3]);
        }
        float4 bld[4];
#pragma unroll
        for (int i = 0; i < 4; ++i)
            bld[i] = *(const float4*)&Wf[(size_t)(k0 + bk_) * 256 + bcol + 4 * i];
        __syncthreads();
        As[akq + 0][ar] = av4.x;
        As[akq + 1][ar] = av4.y;
        As[akq + 2][ar] = av4.z;
        As[akq + 3][ar] = av4.w;
#pragma unroll
        for (int i = 0; i < 4; ++i)
            *(float4*)&Bs[bk_][bcol + 4 * i] = bld[i];
        __syncthreads();
#pragma unroll
        for (int kk = 0; kk < 16; ++kk) {
            float4 a0 = *(const float4*)&As[kk][8 * mg];        // broadcast
            float4 a1 = *(const float4*)&As[kk][8 * mg + 4];    // broadcast
            float4 b0 = *(const float4*)&Bs[kk][4 * cg];        // conflict-free
            float4 b1 = *(const float4*)&Bs[kk][128 + 4 * cg];  // conflict-free
            float am[8] = {a0.x, a0.y, a0.z, a0.w, a1.x, a1.y, a1.z, a1.w};
            float bm[8] = {b0.x, b0.y, b0.z, b0.w, b1.x, b1.y, b1.z, b1.w};
#pragma unroll
            for (int r = 0; r < 8; ++r)
#pragma unroll
                for (int c = 0; c < 8; ++c)
                    acc[r][c] = fmaf(am[r], bm[c], acc[r][c]);
        }
    }

    float biasLo[4], biasHi[4];
#pragma unroll
    for (int c = 0; c < 4; ++c) {
        biasLo[c] = bf[4 * cg + c];
        biasHi[c] = bf[128 + 4 * cg + c];
    }
    const int nn = min(64, N - n0);
#pragma unroll
    for (int r = 0; r < 8; ++r) {
        int row = 8 * mg + r;
        if (row < nn) {
            float4 o;
            o.x = acc[r][0] + biasLo[0];
            o.y = acc[r][1] + biasLo[1];
            o.z = acc[r][2] + biasLo[2];
            o.w = acc[r][3] + biasLo[3];
            *(float4*)&Y2[(size_t)(n0 + row) * 128 + 4 * cg] = o;

            __half2 p0 = __floats2half2_rn(acc[r][4] + biasHi[0],
                                           acc[r][5] + biasHi[1]);
            __half2 p1 = __floats2half2_rn(acc[r][6] + biasHi[2],
                                           acc[r][7] + biasHi[3]);
            uint2 u;
            u.x = *reinterpret_cast<unsigned*>(&p0);
            u.y = *reinterpret_cast<unsigned*>(&p1);
            *(uint2*)&QV[(size_t)(n0 + row) * 64 + 2 * cg] = u;
        }
    }
}

// ---------------------------------------------------------------------------
// CSR scans + scatter.
// ---------------------------------------------------------------------------
__global__ __launch_bounds__(256) void scan1_kernel(
    const int* __restrict__ deg, int* __restrict__ rp1loc,
    int* __restrict__ psum, int N)
{
    __shared__ int s[256];
    const int b = blockIdx.x;
    const int base = b * 1024;
    const int t = threadIdx.x;
    int v[4], sum = 0;
#pragma unroll
    for (int i = 0; i < 4; ++i) {
        int idx = base + t * 4 + i;
        v[i] = (idx < N) ? deg[idx] : 0;
        sum += v[i];
    }
    s[t] = sum;
    __syncthreads();
    for (int off = 1; off < 256; off <<= 1) {
        int x = (t >= off) ? s[t - off] : 0;
        __syncthreads();
        s[t] += x;
        __syncthreads();
    }
    int run = s[t] - sum;
#pragma unroll
    for (int i = 0; i < 4; ++i) {
        run += v[i];
        int idx = base + t * 4 + i;
        if (idx < N) rp1loc[idx] = run;
    }
    if (t == 255) psum[b] = s[255];
}

__global__ __launch_bounds__(256) void scan23_kernel(
    const int* __restrict__ rp1loc, const int* __restrict__ psum,
    int* __restrict__ rowptr, int* __restrict__ cursor, int N, int NBLK)
{
    __shared__ int ps[256];
    const int t = threadIdx.x;
    int c = (t < NBLK) ? psum[t] : 0;
    ps[t] = c;
    __syncthreads();
    for (int off = 1; off < 256; off <<= 1) {
        int x = (t >= off) ? ps[t - off] : 0;
        __syncthreads();
        ps[t] += x;
        __syncthreads();
    }
    for (int i = blockIdx.x * 256 + t; i < N; i += gridDim.x * 256) {
        int k = i >> 10;
        int excl = k ? ps[k - 1] : 0;
        rowptr[i + 1] = rp1loc[i] + excl;
        if (i == 0) cursor[0] = 0;
        else {
            int kp = (i - 1) >> 10;
            int exclp = kp ? ps[kp - 1] : 0;
            cursor[i] = rp1loc[i - 1] + exclp;
        }
    }
    if (blockIdx.x == 0 && t == 0) rowptr[0] = 0;
}

__global__ __launch_bounds__(256) void scatter_kernel(
    const int* __restrict__ ei, int* __restrict__ cursor,
    int* __restrict__ col, int E)
{
    int t = blockIdx.x * 256 + threadIdx.x;
    int T = gridDim.x * 256;
    for (int e = t; e < E; e += T) {
        int d = ei[E + e];
        int pos = atomicAdd(&cursor[d], 1);
        col[pos] = ei[e];
    }
}

// ---------------------------------------------------------------------------
// Aggregation: EDGE-BALANCED node ranges per wave (binary search on rowptr).
// Uniform col reads -> SGPR indices -> saddr QV gathers, 8-deep.
// Fuses sigmoid + BN channel stats + per-graph raw-y sums.
// ---------------------------------------------------------------------------
__device__ __forceinline__ int rp_search(const int* __restrict__ rowptr,
                                         int N, int target)
{
    int lo = 0, hi = N;
    while (lo < hi) {
        int mid = (lo + hi) >> 1;
        if (rowptr[mid + 1] <= target) lo = mid + 1;
        else hi = mid;
    }
    return lo;
}

__global__ __launch_bounds__(256) void agg_kernel(
    const int* __restrict__ rowptr, const int* __restrict__ col,
    const float* __restrict__ Y2, const unsigned* __restrict__ QV,
    const int* __restrict__ batch,
    float* __restrict__ H, float* __restrict__ stats,
    float* __restrict__ gsumy, int N, int Etot)
{
    const int tid = threadIdx.x;
    const int lane = tid & 63;
    const int wid = __builtin_amdgcn_readfirstlane(
        (int)((blockIdx.x * blockDim.x + tid) >> 6));
    const int NW = (gridDim.x * blockDim.x) >> 6;
    const float L2E = 1.44269504f;

    const int tA = (int)(((long long)wid * Etot) / NW);
    const int tB = (int)(((long long)(wid + 1) * Etot) / NW);
    const int nA = (wid == 0) ? 0 : rp_search(rowptr, N, tA);
    const int nB = (wid == NW - 1) ? N : rp_search(rowptr, N, tB);

    float st1 = 0.0f, st2 = 0.0f;
    float gacc = 0.0f;
    int cur = -1;

    for (int n = nA; n < nB; ++n) {
        const int r0 = __builtin_amdgcn_readfirstlane(rowptr[n]);
        const int r1 = __builtin_amdgcn_readfirstlane(rowptr[n + 1]);
        const float* __restrict__ yrow = Y2 + (size_t)n * 128;
        float kk = yrow[lane];
        float acc = yrow[64 + lane];
        const float nkl = kk * (-L2E);

        int e = r0;
        for (; e + 8 <= r1; e += 8) {
            int s[8];
#pragma unroll
            for (int i = 0; i < 8; ++i)
                s[i] = __builtin_amdgcn_readfirstlane(col[e + i]);
            unsigned u[8];
#pragma unroll
            for (int i = 0; i < 8; ++i) u[i] = QV[((size_t)s[i] << 6) + lane];
#pragma unroll
            for (int i = 0; i < 8; ++i) {
                float2 f = __half22float2(*reinterpret_cast<__half2*>(&u[i]));
                float ex = __builtin_amdgcn_exp2f(fmaf(f.x, -L2E, nkl));
                acc = fmaf(__builtin_amdgcn_rcpf(1.0f + ex), f.y, acc);
            }
        }
        for (; e + 4 <= r1; e += 4) {
            int s[4];
#pragma unroll
            for (int i = 0; i < 4; ++i)
                s[i] = __builtin_amdgcn_readfirstlane(col[e + i]);
            unsigned u[4];
#pragma unroll
            for (int i = 0; i < 4; ++i) u[i] = QV[((size_t)s[i] << 6) + lane];
#pragma unroll
            for (int i = 0; i < 4; ++i) {
                float2 f = __half22float2(*reinterpret_cast<__half2*>(&u[i]));
                float ex = __builtin_amdgcn_exp2f(fmaf(f.x, -L2E, nkl));
                acc = fmaf(__builtin_amdgcn_rcpf(1.0f + ex), f.y, acc);
            }
        }
        for (; e < r1; ++e) {
            int s0 = __builtin_amdgcn_readfirstlane(col[e]);
            unsigned u0 = QV[((size_t)s0 << 6) + lane];
            float2 f0 = __half22float2(*reinterpret_cast<__half2*>(&u0));
            float e0 = __builtin_amdgcn_exp2f(fmaf(f0.x, -L2E, nkl));
            acc = fmaf(__builtin_amdgcn_rcpf(1.0f + e0), f0.y, acc);
        }

        float y = __builtin_amdgcn_rcpf(
            1.0f + __builtin_amdgcn_exp2f(acc * (-L2E)));
        H[(size_t)n * 64 + lane] = y;
        st1 += y;
        st2 += y * y;
        int gi = __builtin_amdgcn_readfirstlane(batch[n]);
        if (gi != cur) {
            if (cur >= 0) atomicAdd(&gsumy[cur * 64 + lane], gacc);
            gacc = 0.0f;
            cur = gi;
        }
        gacc += y;
    }
    if (cur >= 0) atomicAdd(&gsumy[cur * 64 + lane], gacc);

    __shared__ float red1[4][64], red2[4][64];
    const int w = tid >> 6;
    red1[w][lane] = st1;
    red2[w][lane] = st2;
    __syncthreads();
    if (tid < 64) {
        float a = red1[0][lane] + red1[1][lane] + red1[2][lane] + red1[3][lane];
        float c = red2[0][lane] + red2[1][lane] + red2[2][lane] + red2[3][lane];
        atomicAdd(&stats[lane], a);
        atomicAdd(&stats[64 + lane], c);
    }
}

// ---------------------------------------------------------------------------
// Head 1: reconstruct BN'd per-graph sums from raw-y sums via affine
//   sum_v = rs*sum_y + cnt*(be - m*rs),  mean = sum_v / max(cnt,1)
// ---------------------------------------------------------------------------
__global__ __launch_bounds__(128) void head1_kernel(
    const float* __restrict__ gsumy0, const float* __restrict__ gsumy1,
    const float* __restrict__ counts,
    const float* __restrict__ stats0, const float* __restrict__ stats1,
    const float* __restrict__ g0, const float* __restrict__ be0,
    const float* __restrict__ g1, const float* __restrict__ be1,
    const float* __restrict__ Wh0, const float* __restrict__ bh0,
    float* __restrict__ t0, float* __restrict__ hstat0, float invN)
{
    const int gr = blockIdx.x;
    const int o = threadIdx.x;
    __shared__ float feat[256];

    const float* st = (o < 64) ? stats0 : stats1;
    const float* gg = (o < 64) ? g0 : g1;
    const float* bb = (o < 64) ? be0 : be1;
    const float* gs = (o < 64) ? gsumy0 : gsumy1;
    int c = o & 63;
    float m = st[c] * invN;
    float var = st[64 + c] * invN - m * m;
    float rs = rsqrtf(var + EPS) * gg[c];
    float off = bb[c] - m * rs;
    float cnt = counts[gr];
    float sv = rs * gs[gr * 64 + c] + cnt * off;
    float inv = __fdividef(1.0f, fmaxf(cnt, 1.0f));
    feat[o] = sv * inv;
    feat[128 + o] = sv;
    __syncthreads();

    float acc = bh0[o];
    for (int j = 0; j < 256; ++j) acc = fmaf(feat[j], Wh0[j * 128 + o], acc);
    float y = sigmoidf_(acc);
    t0[gr * 128 + o] = y;
    atomicAdd(&hstat0[o], y);
    atomicAdd(&hstat0[128 + o], y * y);
}

__global__ __launch_bounds__(64) void head2_kernel(
    const float* __restrict__ t0, const float* __restrict__ hstat0,
    const float* __restrict__ gh0, const float* __restrict__ beh0,
    const float* __restrict__ Wh1, const float* __restrict__ bh1,
    float* __restrict__ t1, float* __restrict__ hstat1)
{
    const int gr = blockIdx.x;
    const int o = threadIdx.x;
    __shared__ float bn0[128];
    const float invG = 1.0f / (float)N_GRAPHS;
    for (int j = o; j < 128; j += 64) {
        float m = hstat0[j] * invG;
        float v = hstat0[128 + j] * invG - m * m;
        bn0[j] = (t0[gr * 128 + j] - m) * rsqrtf(v + EPS) * gh0[j] + beh0[j];
    }
    __syncthreads();
    float acc = bh1[o];
    for (int j = 0; j < 128; ++j) acc = fmaf(bn0[j], Wh1[j * 64 + o], acc);
    float y = sigmoidf_(acc);
    t1[gr * 64 + o] = y;
    atomicAdd(&hstat1[o], y);
    atomicAdd(&hstat1[64 + o], y * y);
}

__global__ __launch_bounds__(64) void head3_kernel(
    const float* __restrict__ t1, const float* __restrict__ hstat1,
    const float* __restrict__ gh1, const float* __restrict__ beh1,
    const float* __restrict__ Wc, const float* __restrict__ bc,
    float* __restrict__ out)
{
    const int gr = blockIdx.x;
    const int o = threadIdx.x;
    const float invG = 1.0f / (float)N_GRAPHS;
    float m = hstat1[o] * invG;
    float v = hstat1[64 + o] * invG - m * m;
    float b = (t1[gr * 64 + o] - m) * rsqrtf(v + EPS) * gh1[o] + beh1[o];
    float p0 = b * Wc[o * 2];
    float p1 = b * Wc[o * 2 + 1];
#pragma unroll
    for (int off = 32; off > 0; off >>= 1) {
        p0 += __shfl_down(p0, off);
        p1 += __shfl_down(p1, off);
    }
    if (o == 0) {
        out[gr * 2] = p0 + bc[0];
        out[gr * 2 + 1] = p1 + bc[1];
    }
}

// ---------------------------------------------------------------------------
extern "C" void kernel_launch(void* const* d_in, const int* in_sizes, int n_in,
                              void* d_out, int out_size, void* d_ws, size_t ws_size,
                              hipStream_t stream)
{
    const float* x     = (const float*)d_in[0];
    const int*   ei    = (const int*)d_in[1];
    const int*   batch = (const int*)d_in[2];
    const int N = in_sizes[2];
    const int E = in_sizes[1] / 2;
    const int NCHUNK = (N + 1023) / 1024;

    const float *Wk0 = (const float*)d_in[3],  *bk0 = (const float*)d_in[4];
    const float *Wq0 = (const float*)d_in[5],  *bq0 = (const float*)d_in[6];
    const float *Wv0 = (const float*)d_in[7],  *bv0 = (const float*)d_in[8];
    const float *Ws0 = (const float*)d_in[9],  *cb0 = (const float*)d_in[10];
    const float *g0  = (const float*)d_in[11], *be0 = (const float*)d_in[12];
    const float *Wk1 = (const float*)d_in[13], *bk1 = (const float*)d_in[14];
    const float *Wq1 = (const float*)d_in[15], *bq1 = (const float*)d_in[16];
    const float *Wv1 = (const float*)d_in[17], *bv1 = (const float*)d_in[18];
    const float *Ws1 = (const float*)d_in[19], *cb1 = (const float*)d_in[20];
    const float *g1  = (const float*)d_in[21], *be1 = (const float*)d_in[22];
    const float *Wh0 = (const float*)d_in[23], *bh0 = (const float*)d_in[24];
    const float *gh0 = (const float*)d_in[25], *beh0 = (const float*)d_in[26];
    const float *Wh1 = (const float*)d_in[27], *bh1 = (const float*)d_in[28];
    const float *gh1 = (const float*)d_in[29], *beh1 = (const float*)d_in[30];
    const float *Wc  = (const float*)d_in[31], *bc  = (const float*)d_in[32];

    float*    ws = (float*)d_ws;
    float*    Y2 = ws;                          // N*128 fp32 [k|s]
    unsigned* QV = (unsigned*)(Y2 + (size_t)N * 128);  // N*64 packed fp16 q|v
    float*    H  = (float*)(QV + (size_t)N * 64);      // N*64 fp32 (raw y)
    int*   col     = (int*)(H + (size_t)N * 64);       // E
    int*   rowptr  = col + E;             // N+1
    int*   rp1loc  = rowptr + N + 1;      // N
    int*   cursor  = rp1loc + N;          // N
    int*   psum    = cursor + N;          // 256
    float* Wf0  = (float*)(psum + 256);   // 128*256
    float* bf0  = Wf0 + 128 * 256;        // 256
    float* Wf1  = bf0 + 256;              // 64*256
    float* bf1  = Wf1 + 64 * 256;         // 256
    int*   deg     = (int*)(bf1 + 256);   // N    <-- zero zone starts here
    float* gsumy0 = (float*)(deg + N);    // 128*64
    float* gsumy1 = gsumy0 + 128 * 64;    // 128*64
    float* counts = gsumy1 + 128 * 64;    // 128
    float* stats0 = counts + 128;         // 128
    float* stats1 = stats0 + 128;         // 128
    float* hstat0 = stats1 + 128;         // 256
    float* hstat1 = hstat0 + 256;         // 128
    size_t zbytes = (size_t)N * sizeof(int) +
                    (size_t)(128 * 64 * 2 + 128 * 3 + 256 + 128) * sizeof(float);
    float* t0 = hstat1 + 128;             // 128*128
    float* t1 = t0 + 128 * 128;           // 128*64

    hipMemsetAsync(deg, 0, zbytes, stream);

    // ---- fused prep (deg + counts + weight fusion) ----
    prep_kernel<<<400, 256, 0, stream>>>(
        ei, deg, E, batch, counts, N,
        Wk0, bk0, Wq0, bq0, Wv0, bv0, Ws0, cb0, Wf0, bf0,
        Wk1, bk1, Wq1, bq1, Wv1, bv1, Ws1, cb1, Wf1, bf1);
    scan1_kernel<<<NCHUNK, 256, 0, stream>>>(deg, rp1loc, psum, N);
    scan23_kernel<<<256, 256, 0, stream>>>(rp1loc, psum, rowptr, cursor, N, NCHUNK);
    scatter_kernel<<<512, 256, 0, stream>>>(ei, cursor, col, E);

    const float invN = 1.0f / (float)N;
    const int projBlocks = (N + 63) / 64;

    // ---- layer 0 ----
    proj_kernel<128, false><<<projBlocks, 256, 0, stream>>>(
        x, Wf0, bf0, nullptr, nullptr, nullptr, invN, Y2, QV, N);
    agg_kernel<<<2048, 256, 0, stream>>>(rowptr, col, Y2, QV, batch,
                                         H, stats0, gsumy0, N, E);

    // ---- layer 1 (BN affine computed in-kernel from stats0) ----
    proj_kernel<64, true><<<projBlocks, 256, 0, stream>>>(
        H, Wf1, bf1, stats0, g0, be0, invN, Y2, QV, N);
    agg_kernel<<<2048, 256, 0, stream>>>(rowptr, col, Y2, QV, batch,
                                         H, stats1, gsumy1, N, E);

    // ---- head ----
    head1_kernel<<<128, 128, 0, stream>>>(gsumy0, gsumy1, counts,
                                          stats0, stats1, g0, be0, g1, be1,
                                          Wh0, bh0, t0, hstat0, invN);
    head2_kernel<<<128, 64, 0, stream>>>(t0, hstat0, gh0, beh0, Wh1, bh1, t1, hstat1);
    head3_kernel<<<128, 64, 0, stream>>>(t1, hstat1, gh1, beh1, Wc, bc, (float*)d_out);
}

// Round 13
// 660.233 us; speedup vs baseline: 1.0802x; 1.0802x over previous
//
#include <hip/hip_runtime.h>
#include <hip/hip_fp16.h>
#include <math.h>

#define EPS 1e-5f
#define N_GRAPHS 128

__device__ __forceinline__ float sigmoidf_(float x) {
    return __fdividef(1.0f, 1.0f + __expf(-x));
}

// ---------------------------------------------------------------------------
// Fused prep: block-range partition.
//  [0,256):  deg histogram      [256,320): fuse_w layer0 (K=128)
//  [320,384): fuse_w layer1 (K=64)        [384,400): per-graph counts
// Fused col c: [0,64)=Wk, [64,128)=Ws, [128,256)= interleaved (q,v).
// ---------------------------------------------------------------------------
__device__ __forceinline__ void fuse_w_body(
    int b0, int blk, int tid,
    const float* __restrict__ Wk, const float* __restrict__ bk,
    const float* __restrict__ Wq, const float* __restrict__ bq,
    const float* __restrict__ Wv, const float* __restrict__ bv,
    const float* __restrict__ Ws, const float* __restrict__ cbv,
    float* __restrict__ Wf, float* __restrict__ bf, int K)
{
    int t = (blk - b0) * 256 + tid;
    int total = K * 256;
    for (int i = t; i < total; i += 64 * 256) {
        int k = i >> 8, c = i & 255;
        const float* W;
        int cc;
        if (c < 64)       { W = Wk; cc = c; }
        else if (c < 128) { W = Ws; cc = c - 64; }
        else { int j = c - 128; cc = j >> 1; W = (j & 1) ? Wv : Wq; }
        Wf[i] = W[k * 64 + cc];
    }
    if (t < 256) {
        int c = t;
        const float* b;
        int cc;
        if (c < 64)       { b = bk;  cc = c; }
        else if (c < 128) { b = cbv; cc = c - 64; }
        else { int j = c - 128; cc = j >> 1; b = (j & 1) ? bv : bq; }
        bf[t] = b[cc];
    }
}

__global__ __launch_bounds__(256) void prep_kernel(
    const int* __restrict__ ei, int* __restrict__ deg, int E,
    const int* __restrict__ batch, float* __restrict__ counts, int N,
    const float* __restrict__ Wk0, const float* __restrict__ bk0,
    const float* __restrict__ Wq0, const float* __restrict__ bq0,
    const float* __restrict__ Wv0, const float* __restrict__ bv0,
    const float* __restrict__ Ws0, const float* __restrict__ cb0,
    float* __restrict__ Wf0, float* __restrict__ bf0,
    const float* __restrict__ Wk1, const float* __restrict__ bk1,
    const float* __restrict__ Wq1, const float* __restrict__ bq1,
    const float* __restrict__ Wv1, const float* __restrict__ bv1,
    const float* __restrict__ Ws1, const float* __restrict__ cb1,
    float* __restrict__ Wf1, float* __restrict__ bf1)
{
    const int blk = blockIdx.x;
    const int tid = threadIdx.x;
    if (blk < 256) {
        int t = blk * 256 + tid;
        for (int e = t; e < E; e += 256 * 256) atomicAdd(&deg[ei[E + e]], 1);
    } else if (blk < 320) {
        fuse_w_body(256, blk, tid, Wk0, bk0, Wq0, bq0, Wv0, bv0, Ws0, cb0,
                    Wf0, bf0, 128);
    } else if (blk < 384) {
        fuse_w_body(320, blk, tid, Wk1, bk1, Wq1, bq1, Wv1, bv1, Ws1, cb1,
                    Wf1, bf1, 64);
    } else {
        const int t = (blk - 384) * 256 + tid;
        const int T = 16 * 256;
        const int chunk = (N + T - 1) / T;
        const int a = t * chunk;
        const int b = min(N, a + chunk);
        int cur = -1;
        float c = 0.0f;
        for (int n = a; n < b; ++n) {
            int gi = batch[n];
            if (gi != cur) {
                if (cur >= 0) atomicAdd(&counts[cur], c);
                cur = gi;
                c = 0.0f;
            }
            c += 1.0f;
        }
        if (cur >= 0) atomicAdd(&counts[cur], c);
    }
}

// ---------------------------------------------------------------------------
// Projection (r9 version): LDS-tiled fp32 GEMM, fused cols. Tile M=64 x N=128
// (blockIdx&1 = nb). Per-thread 8x4 acc (32 regs -> NO SPILL).
// nb=0 -> fp32 [k|s] to Y2[N][128]; nb=1 -> fp16-packed (q,v) to QV[N][64].
// AFF: BN affine computed in-kernel from stats/g/be, applied while staging X.
// ---------------------------------------------------------------------------
template <int K, bool AFF>
__global__ __launch_bounds__(256) void proj_kernel(
    const float* __restrict__ X, const float* __restrict__ Wf,
    const float* __restrict__ bf,
    const float* __restrict__ stats, const float* __restrict__ g,
    const float* __restrict__ be, float invN,
    float* __restrict__ Y2, unsigned* __restrict__ QV, int N)
{
    __shared__ __attribute__((aligned(16))) float As[16][72];
    __shared__ __attribute__((aligned(16))) float Bs[16][128];
    const int tid = threadIdx.x;
    const int nb = blockIdx.x & 1;
    const int n0 = (blockIdx.x >> 1) * 64;
    const int cg = tid & 31;
    const int mg = tid >> 5;
    const int ar = tid >> 2, akq = (tid & 3) * 4;
    const int bk_ = tid >> 4, bcol = (tid & 15) * 8;

    float acc[8][4];
#pragma unroll
    for (int r = 0; r < 8; ++r)
#pragma unroll
        for (int j = 0; j < 4; ++j) acc[r][j] = 0.0f;

    for (int k0 = 0; k0 < K; k0 += 16) {
        float4 av4 = make_float4(0.f, 0.f, 0.f, 0.f);
        int row = n0 + ar;
        if (row < N) av4 = *(const float4*)&X[(size_t)row * K + k0 + akq];
        if constexpr (AFF) {
            float a4[4], b4[4];
#pragma unroll
            for (int i = 0; i < 4; ++i) {
                int c = k0 + akq + i;
                float m = stats[c] * invN;
                float vv = stats[64 + c] * invN - m * m;
                float rs = rsqrtf(vv + EPS) * g[c];
                a4[i] = rs;
                b4[i] = be[c] - m * rs;
            }
            av4.x = fmaf(av4.x, a4[0], b4[0]);
            av4.y = fmaf(av4.y, a4[1], b4[1]);
            av4.z = fmaf(av4.z, a4[2], b4[2]);
            av4.w = fmaf(av4.w, a4[3], b4[3]);
        }
        const float4 b0 = *(const float4*)&Wf[(size_t)(k0 + bk_) * 256 + nb * 128 + bcol];
        const float4 b1 = *(const float4*)&Wf[(size_t)(k0 + bk_) * 256 + nb * 128 + bcol + 4];
        __syncthreads();
        As[akq + 0][ar] = av4.x;
        As[akq + 1][ar] = av4.y;
        As[akq + 2][ar] = av4.z;
        As[akq + 3][ar] = av4.w;
        *(float4*)&Bs[bk_][bcol] = b0;
        *(float4*)&Bs[bk_][bcol + 4] = b1;
        __syncthreads();
#pragma unroll
        for (int kk = 0; kk < 16; ++kk) {
            float4 a0 = *(const float4*)&As[kk][8 * mg];
            float4 a1 = *(const float4*)&As[kk][8 * mg + 4];
            float4 bv = *(const float4*)&Bs[kk][4 * cg];
            float am[8] = {a0.x, a0.y, a0.z, a0.w, a1.x, a1.y, a1.z, a1.w};
#pragma unroll
            for (int r = 0; r < 8; ++r) {
                acc[r][0] = fmaf(am[r], bv.x, acc[r][0]);
                acc[r][1] = fmaf(am[r], bv.y, acc[r][1]);
                acc[r][2] = fmaf(am[r], bv.z, acc[r][2]);
                acc[r][3] = fmaf(am[r], bv.w, acc[r][3]);
            }
        }
    }

    float4 bias;
    bias.x = bf[nb * 128 + 4 * cg + 0];
    bias.y = bf[nb * 128 + 4 * cg + 1];
    bias.z = bf[nb * 128 + 4 * cg + 2];
    bias.w = bf[nb * 128 + 4 * cg + 3];
    const int nn = min(64, N - n0);
    if (nb == 0) {
#pragma unroll
        for (int r = 0; r < 8; ++r) {
            int row = 8 * mg + r;
            if (row < nn) {
                float4 o;
                o.x = acc[r][0] + bias.x;
                o.y = acc[r][1] + bias.y;
                o.z = acc[r][2] + bias.z;
                o.w = acc[r][3] + bias.w;
                *(float4*)&Y2[(size_t)(n0 + row) * 128 + 4 * cg] = o;
            }
        }
    } else {
#pragma unroll
        for (int r = 0; r < 8; ++r) {
            int row = 8 * mg + r;
            if (row < nn) {
                __half2 p0 = __floats2half2_rn(acc[r][0] + bias.x, acc[r][1] + bias.y);
                __half2 p1 = __floats2half2_rn(acc[r][2] + bias.z, acc[r][3] + bias.w);
                uint2 u;
                u.x = *reinterpret_cast<unsigned*>(&p0);
                u.y = *reinterpret_cast<unsigned*>(&p1);
                *(uint2*)&QV[(size_t)(n0 + row) * 64 + 2 * cg] = u;
            }
        }
    }
}

// ---------------------------------------------------------------------------
// CSR scans + scatter.
// ---------------------------------------------------------------------------
__global__ __launch_bounds__(256) void scan1_kernel(
    const int* __restrict__ deg, int* __restrict__ rp1loc,
    int* __restrict__ psum, int N)
{
    __shared__ int s[256];
    const int b = blockIdx.x;
    const int base = b * 1024;
    const int t = threadIdx.x;
    int v[4], sum = 0;
#pragma unroll
    for (int i = 0; i < 4; ++i) {
        int idx = base + t * 4 + i;
        v[i] = (idx < N) ? deg[idx] : 0;
        sum += v[i];
    }
    s[t] = sum;
    __syncthreads();
    for (int off = 1; off < 256; off <<= 1) {
        int x = (t >= off) ? s[t - off] : 0;
        __syncthreads();
        s[t] += x;
        __syncthreads();
    }
    int run = s[t] - sum;
#pragma unroll
    for (int i = 0; i < 4; ++i) {
        run += v[i];
        int idx = base + t * 4 + i;
        if (idx < N) rp1loc[idx] = run;
    }
    if (t == 255) psum[b] = s[255];
}

__global__ __launch_bounds__(256) void scan23_kernel(
    const int* __restrict__ rp1loc, const int* __restrict__ psum,
    int* __restrict__ rowptr, int* __restrict__ cursor, int N, int NBLK)
{
    __shared__ int ps[256];
    const int t = threadIdx.x;
    int c = (t < NBLK) ? psum[t] : 0;
    ps[t] = c;
    __syncthreads();
    for (int off = 1; off < 256; off <<= 1) {
        int x = (t >= off) ? ps[t - off] : 0;
        __syncthreads();
        ps[t] += x;
        __syncthreads();
    }
    for (int i = blockIdx.x * 256 + t; i < N; i += gridDim.x * 256) {
        int k = i >> 10;
        int excl = k ? ps[k - 1] : 0;
        rowptr[i + 1] = rp1loc[i] + excl;
        if (i == 0) cursor[0] = 0;
        else {
            int kp = (i - 1) >> 10;
            int exclp = kp ? ps[kp - 1] : 0;
            cursor[i] = rp1loc[i - 1] + exclp;
        }
    }
    if (blockIdx.x == 0 && t == 0) rowptr[0] = 0;
}

__global__ __launch_bounds__(256) void scatter_kernel(
    const int* __restrict__ ei, int* __restrict__ cursor,
    int* __restrict__ col, int E)
{
    int t = blockIdx.x * 256 + threadIdx.x;
    int T = gridDim.x * 256;
    for (int e = t; e < E; e += T) {
        int d = ei[E + e];
        int pos = atomicAdd(&cursor[d], 1);
        col[pos] = ei[e];
    }
}

// ---------------------------------------------------------------------------
// Aggregation: EDGE-BALANCED node ranges per wave (binary search on rowptr).
// Uniform col reads -> SGPR indices -> saddr QV gathers, 8-deep.
// Fuses sigmoid + BN channel stats + per-graph raw-y sums.
// ---------------------------------------------------------------------------
__device__ __forceinline__ int rp_search(const int* __restrict__ rowptr,
                                         int N, int target)
{
    int lo = 0, hi = N;
    while (lo < hi) {
        int mid = (lo + hi) >> 1;
        if (rowptr[mid + 1] <= target) lo = mid + 1;
        else hi = mid;
    }
    return lo;
}

__global__ __launch_bounds__(256) void agg_kernel(
    const int* __restrict__ rowptr, const int* __restrict__ col,
    const float* __restrict__ Y2, const unsigned* __restrict__ QV,
    const int* __restrict__ batch,
    float* __restrict__ H, float* __restrict__ stats,
    float* __restrict__ gsumy, int N, int Etot)
{
    const int tid = threadIdx.x;
    const int lane = tid & 63;
    const int wid = __builtin_amdgcn_readfirstlane(
        (int)((blockIdx.x * blockDim.x + tid) >> 6));
    const int NW = (gridDim.x * blockDim.x) >> 6;
    const float L2E = 1.44269504f;

    const int tA = (int)(((long long)wid * Etot) / NW);
    const int tB = (int)(((long long)(wid + 1) * Etot) / NW);
    const int nA = (wid == 0) ? 0 : rp_search(rowptr, N, tA);
    const int nB = (wid == NW - 1) ? N : rp_search(rowptr, N, tB);

    float st1 = 0.0f, st2 = 0.0f;
    float gacc = 0.0f;
    int cur = -1;

    for (int n = nA; n < nB; ++n) {
        const int r0 = __builtin_amdgcn_readfirstlane(rowptr[n]);
        const int r1 = __builtin_amdgcn_readfirstlane(rowptr[n + 1]);
        const float* __restrict__ yrow = Y2 + (size_t)n * 128;
        float kk = yrow[lane];
        float acc = yrow[64 + lane];
        const float nkl = kk * (-L2E);

        int e = r0;
        for (; e + 8 <= r1; e += 8) {
            int s[8];
#pragma unroll
            for (int i = 0; i < 8; ++i)
                s[i] = __builtin_amdgcn_readfirstlane(col[e + i]);
            unsigned u[8];
#pragma unroll
            for (int i = 0; i < 8; ++i) u[i] = QV[((size_t)s[i] << 6) + lane];
#pragma unroll
            for (int i = 0; i < 8; ++i) {
                float2 f = __half22float2(*reinterpret_cast<__half2*>(&u[i]));
                float ex = __builtin_amdgcn_exp2f(fmaf(f.x, -L2E, nkl));
                acc = fmaf(__builtin_amdgcn_rcpf(1.0f + ex), f.y, acc);
            }
        }
        for (; e + 4 <= r1; e += 4) {
            int s[4];
#pragma unroll
            for (int i = 0; i < 4; ++i)
                s[i] = __builtin_amdgcn_readfirstlane(col[e + i]);
            unsigned u[4];
#pragma unroll
            for (int i = 0; i < 4; ++i) u[i] = QV[((size_t)s[i] << 6) + lane];
#pragma unroll
            for (int i = 0; i < 4; ++i) {
                float2 f = __half22float2(*reinterpret_cast<__half2*>(&u[i]));
                float ex = __builtin_amdgcn_exp2f(fmaf(f.x, -L2E, nkl));
                acc = fmaf(__builtin_amdgcn_rcpf(1.0f + ex), f.y, acc);
            }
        }
        for (; e < r1; ++e) {
            int s0 = __builtin_amdgcn_readfirstlane(col[e]);
            unsigned u0 = QV[((size_t)s0 << 6) + lane];
            float2 f0 = __half22float2(*reinterpret_cast<__half2*>(&u0));
            float e0 = __builtin_amdgcn_exp2f(fmaf(f0.x, -L2E, nkl));
            acc = fmaf(__builtin_amdgcn_rcpf(1.0f + e0), f0.y, acc);
        }

        float y = __builtin_amdgcn_rcpf(
            1.0f + __builtin_amdgcn_exp2f(acc * (-L2E)));
        H[(size_t)n * 64 + lane] = y;
        st1 += y;
        st2 += y * y;
        int gi = __builtin_amdgcn_readfirstlane(batch[n]);
        if (gi != cur) {
            if (cur >= 0) atomicAdd(&gsumy[cur * 64 + lane], gacc);
            gacc = 0.0f;
            cur = gi;
        }
        gacc += y;
    }
    if (cur >= 0) atomicAdd(&gsumy[cur * 64 + lane], gacc);

    __shared__ float red1[4][64], red2[4][64];
    const int w = tid >> 6;
    red1[w][lane] = st1;
    red2[w][lane] = st2;
    __syncthreads();
    if (tid < 64) {
        float a = red1[0][lane] + red1[1][lane] + red1[2][lane] + red1[3][lane];
        float c = red2[0][lane] + red2[1][lane] + red2[2][lane] + red2[3][lane];
        atomicAdd(&stats[lane], a);
        atomicAdd(&stats[64 + lane], c);
    }
}

// ---------------------------------------------------------------------------
// Head 1: reconstruct BN'd per-graph sums from raw-y sums via affine
//   sum_v = rs*sum_y + cnt*(be - m*rs),  mean = sum_v / max(cnt,1)
// ---------------------------------------------------------------------------
__global__ __launch_bounds__(128) void head1_kernel(
    const float* __restrict__ gsumy0, const float* __restrict__ gsumy1,
    const float* __restrict__ counts,
    const float* __restrict__ stats0, const float* __restrict__ stats1,
    const float* __restrict__ g0, const float* __restrict__ be0,
    const float* __restrict__ g1, const float* __restrict__ be1,
    const float* __restrict__ Wh0, const float* __restrict__ bh0,
    float* __restrict__ t0, float* __restrict__ hstat0, float invN)
{
    const int gr = blockIdx.x;
    const int o = threadIdx.x;
    __shared__ float feat[256];

    const float* st = (o < 64) ? stats0 : stats1;
    const float* gg = (o < 64) ? g0 : g1;
    const float* bb = (o < 64) ? be0 : be1;
    const float* gs = (o < 64) ? gsumy0 : gsumy1;
    int c = o & 63;
    float m = st[c] * invN;
    float var = st[64 + c] * invN - m * m;
    float rs = rsqrtf(var + EPS) * gg[c];
    float off = bb[c] - m * rs;
    float cnt = counts[gr];
    float sv = rs * gs[gr * 64 + c] + cnt * off;
    float inv = __fdividef(1.0f, fmaxf(cnt, 1.0f));
    feat[o] = sv * inv;
    feat[128 + o] = sv;
    __syncthreads();

    float acc = bh0[o];
    for (int j = 0; j < 256; ++j) acc = fmaf(feat[j], Wh0[j * 128 + o], acc);
    float y = sigmoidf_(acc);
    t0[gr * 128 + o] = y;
    atomicAdd(&hstat0[o], y);
    atomicAdd(&hstat0[128 + o], y * y);
}

__global__ __launch_bounds__(64) void head2_kernel(
    const float* __restrict__ t0, const float* __restrict__ hstat0,
    const float* __restrict__ gh0, const float* __restrict__ beh0,
    const float* __restrict__ Wh1, const float* __restrict__ bh1,
    float* __restrict__ t1, float* __restrict__ hstat1)
{
    const int gr = blockIdx.x;
    const int o = threadIdx.x;
    __shared__ float bn0[128];
    const float invG = 1.0f / (float)N_GRAPHS;
    for (int j = o; j < 128; j += 64) {
        float m = hstat0[j] * invG;
        float v = hstat0[128 + j] * invG - m * m;
        bn0[j] = (t0[gr * 128 + j] - m) * rsqrtf(v + EPS) * gh0[j] + beh0[j];
    }
    __syncthreads();
    float acc = bh1[o];
    for (int j = 0; j < 128; ++j) acc = fmaf(bn0[j], Wh1[j * 64 + o], acc);
    float y = sigmoidf_(acc);
    t1[gr * 64 + o] = y;
    atomicAdd(&hstat1[o], y);
    atomicAdd(&hstat1[64 + o], y * y);
}

__global__ __launch_bounds__(64) void head3_kernel(
    const float* __restrict__ t1, const float* __restrict__ hstat1,
    const float* __restrict__ gh1, const float* __restrict__ beh1,
    const float* __restrict__ Wc, const float* __restrict__ bc,
    float* __restrict__ out)
{
    const int gr = blockIdx.x;
    const int o = threadIdx.x;
    const float invG = 1.0f / (float)N_GRAPHS;
    float m = hstat1[o] * invG;
    float v = hstat1[64 + o] * invG - m * m;
    float b = (t1[gr * 64 + o] - m) * rsqrtf(v + EPS) * gh1[o] + beh1[o];
    float p0 = b * Wc[o * 2];
    float p1 = b * Wc[o * 2 + 1];
#pragma unroll
    for (int off = 32; off > 0; off >>= 1) {
        p0 += __shfl_down(p0, off);
        p1 += __shfl_down(p1, off);
    }
    if (o == 0) {
        out[gr * 2] = p0 + bc[0];
        out[gr * 2 + 1] = p1 + bc[1];
    }
}

// ---------------------------------------------------------------------------
extern "C" void kernel_launch(void* const* d_in, const int* in_sizes, int n_in,
                              void* d_out, int out_size, void* d_ws, size_t ws_size,
                              hipStream_t stream)
{
    const float* x     = (const float*)d_in[0];
    const int*   ei    = (const int*)d_in[1];
    const int*   batch = (const int*)d_in[2];
    const int N = in_sizes[2];
    const int E = in_sizes[1] / 2;
    const int NCHUNK = (N + 1023) / 1024;

    const float *Wk0 = (const float*)d_in[3],  *bk0 = (const float*)d_in[4];
    const float *Wq0 = (const float*)d_in[5],  *bq0 = (const float*)d_in[6];
    const float *Wv0 = (const float*)d_in[7],  *bv0 = (const float*)d_in[8];
    const float *Ws0 = (const float*)d_in[9],  *cb0 = (const float*)d_in[10];
    const float *g0  = (const float*)d_in[11], *be0 = (const float*)d_in[12];
    const float *Wk1 = (const float*)d_in[13], *bk1 = (const float*)d_in[14];
    const float *Wq1 = (const float*)d_in[15], *bq1 = (const float*)d_in[16];
    const float *Wv1 = (const float*)d_in[17], *bv1 = (const float*)d_in[18];
    const float *Ws1 = (const float*)d_in[19], *cb1 = (const float*)d_in[20];
    const float *g1  = (const float*)d_in[21], *be1 = (const float*)d_in[22];
    const float *Wh0 = (const float*)d_in[23], *bh0 = (const float*)d_in[24];
    const float *gh0 = (const float*)d_in[25], *beh0 = (const float*)d_in[26];
    const float *Wh1 = (const float*)d_in[27], *bh1 = (const float*)d_in[28];
    const float *gh1 = (const float*)d_in[29], *beh1 = (const float*)d_in[30];
    const float *Wc  = (const float*)d_in[31], *bc  = (const float*)d_in[32];

    float*    ws = (float*)d_ws;
    float*    Y2 = ws;                          // N*128 fp32 [k|s]
    unsigned* QV = (unsigned*)(Y2 + (size_t)N * 128);  // N*64 packed fp16 q|v
    float*    H  = (float*)(QV + (size_t)N * 64);      // N*64 fp32 (raw y)
    int*   col     = (int*)(H + (size_t)N * 64);       // E
    int*   rowptr  = col + E;             // N+1
    int*   rp1loc  = rowptr + N + 1;      // N
    int*   cursor  = rp1loc + N;          // N
    int*   psum    = cursor + N;          // 256
    float* Wf0  = (float*)(psum + 256);   // 128*256
    float* bf0  = Wf0 + 128 * 256;        // 256
    float* Wf1  = bf0 + 256;              // 64*256
    float* bf1  = Wf1 + 64 * 256;         // 256
    int*   deg     = (int*)(bf1 + 256);   // N    <-- zero zone starts here
    float* gsumy0 = (float*)(deg + N);    // 128*64
    float* gsumy1 = gsumy0 + 128 * 64;    // 128*64
    float* counts = gsumy1 + 128 * 64;    // 128
    float* stats0 = counts + 128;         // 128
    float* stats1 = stats0 + 128;         // 128
    float* hstat0 = stats1 + 128;         // 256
    float* hstat1 = hstat0 + 256;         // 128
    size_t zbytes = (size_t)N * sizeof(int) +
                    (size_t)(128 * 64 * 2 + 128 * 3 + 256 + 128) * sizeof(float);
    float* t0 = hstat1 + 128;             // 128*128
    float* t1 = t0 + 128 * 128;           // 128*64

    hipMemsetAsync(deg, 0, zbytes, stream);

    // ---- fused prep (deg + counts + weight fusion) ----
    prep_kernel<<<400, 256, 0, stream>>>(
        ei, deg, E, batch, counts, N,
        Wk0, bk0, Wq0, bq0, Wv0, bv0, Ws0, cb0, Wf0, bf0,
        Wk1, bk1, Wq1, bq1, Wv1, bv1, Ws1, cb1, Wf1, bf1);
    scan1_kernel<<<NCHUNK, 256, 0, stream>>>(deg, rp1loc, psum, N);
    scan23_kernel<<<256, 256, 0, stream>>>(rp1loc, psum, rowptr, cursor, N, NCHUNK);
    scatter_kernel<<<512, 256, 0, stream>>>(ei, cursor, col, E);

    const float invN = 1.0f / (float)N;
    const int projBlocks = ((N + 63) / 64) * 2;

    // ---- layer 0 ----
    proj_kernel<128, false><<<projBlocks, 256, 0, stream>>>(
        x, Wf0, bf0, nullptr, nullptr, nullptr, invN, Y2, QV, N);
    agg_kernel<<<2048, 256, 0, stream>>>(rowptr, col, Y2, QV, batch,
                                         H, stats0, gsumy0, N, E);

    // ---- layer 1 (BN affine computed in-kernel from stats0) ----
    proj_kernel<64, true><<<projBlocks, 256, 0, stream>>>(
        H, Wf1, bf1, stats0, g0, be0, invN, Y2, QV, N);
    agg_kernel<<<2048, 256, 0, stream>>>(rowptr, col, Y2, QV, batch,
                                         H, stats1, gsumy1, N, E);

    // ---- head ----
    head1_kernel<<<128, 128, 0, stream>>>(gsumy0, gsumy1, counts,
                                          stats0, stats1, g0, be0, g1, be1,
                                          Wh0, bh0, t0, hstat0, invN);
    head2_kernel<<<128, 64, 0, stream>>>(t0, hstat0, gh0, beh0, Wh1, bh1, t1, hstat1);
    head3_kernel<<<128, 64, 0, stream>>>(t1, hstat1, gh1, beh1, Wc, bc, (float*)d_out);
}